// Round 11
// baseline (901.870 us; speedup 1.0000x reference)
//
#include <hip/hip_runtime.h>

#define BT    8      // batch tile per block
#define HID   64
#define SEQ   512
#define NOUT  12
#define GRS   9      // gate-row stride in floats (8 batches + 1 pad)

typedef float  f32x4  __attribute__((ext_vector_type(4)));
typedef short  bf16x8 __attribute__((ext_vector_type(8)));
typedef unsigned int u32;

union FW { bf16x8 v; u32 w[4]; uint4 q; };

__device__ __forceinline__ float sigf(float x)       { return 1.f / (1.f + __expf(-x)); }
__device__ __forceinline__ float tanhf_fast(float x) { return 1.f - 2.f / (1.f + __expf(2.f * x)); }
__device__ __forceinline__ u32  packbf2(float a, float b) {
    return (__float_as_uint(a) >> 16) | (__float_as_uint(b) & 0xFFFF0000u);
}
__device__ __forceinline__ float trunc_bf(float a) {
    return __uint_as_float(__float_as_uint(a) & 0xFFFF0000u);
}
// Split 8 consecutive f32 into hi/lo bf16x8 fragments (element j <-> k-offset j).
__device__ __forceinline__ void split8(const float* src, bf16x8& hi, bf16x8& lo) {
    float f[8];
    *(float4*)&f[0] = *(const float4*)src;
    *(float4*)&f[4] = *(const float4*)(src + 4);
    FW H, L;
#pragma unroll
    for (int i = 0; i < 4; ++i) {
        float a = f[2*i], b = f[2*i+1];
        H.w[i] = packbf2(a, b);
        L.w[i] = packbf2(a - trunc_bf(a), b - trunc_bf(b));
    }
    hi = H.v; lo = L.v;
}

#define MFMA(A, B, C) __builtin_amdgcn_mfma_f32_16x16x32_bf16((A), (B), (C), 0, 0, 0)

// Fragment store: per (dbuf, layer, hi/lo, kt) a 256-dword block of 64 x 16B
// chunks; chunk for MFMA-lane L at position swz(L) = L ^ (L>>3). Reads are
// lane-linear (<=2-way banks); ew-side writes also <=2-way.
#define HFB(db, ly, hl, kt) ((((((db)*2 + (ly))*2 + (hl))*2 + (kt)) << 8))
__device__ __forceinline__ int swz(int c) { return c ^ (c >> 3); }

// Round-10 structure (16 balanced waves, 1 block/CU, swizzled frag layout,
// gl gate round-trip, distributed ew). Single change: the 18 MFMAs are now
// SIX INDEPENDENT depth-3 accumulator chains issued round-robin (same-chain
// issues ~29 cyc apart > MFMA latency) instead of 6- and 12-deep serial
// chains -> MFMA pipe stops stalling on accumulate dependencies.
__global__ void __launch_bounds__(1024)
lstm2_fused(
    const float* __restrict__ x,      // [B, SEQ, 1]
    const float* __restrict__ w_ih0,  // [256, 1]
    const float* __restrict__ w_hh0,  // [256, 64]
    const float* __restrict__ b_ih0,  // [256]
    const float* __restrict__ b_hh0,  // [256]
    const float* __restrict__ w_ih1,  // [256, 64]
    const float* __restrict__ w_hh1,  // [256, 64]
    const float* __restrict__ b_ih1,  // [256]
    const float* __restrict__ b_hh1,  // [256]
    const float* __restrict__ fc_w,   // [12, 64]
    const float* __restrict__ fc_b,   // [12]
    float* __restrict__ out)          // [B, 12]
{
    __shared__ float xs[BT][SEQ];          // 16 KB
    __shared__ u32   hf[4096];             // 16 KB [dbuf][layer][hi/lo][kt][chunk]
    __shared__ float gl[2][256][GRS];      // 18.4 KB [layer][gate-row][batch]
    __shared__ float h1last[BT][HID + 4];  // 2.1 KB

    const int tid  = threadIdx.x;
    const int wid  = tid >> 6;        // row-tile band (0..15)
    const int lane = tid & 63;
    const int n    = lane & 15;       // MFMA A-row / B-col (batch) lane index
    const int qg   = lane >> 4;       // lane k-group (0..3)
    const int b0   = blockIdx.x * BT;

    // ew role: thread <-> (layer, batch, unit)
    const int el = tid >> 9;          // 0..1
    const int eb = (tid >> 6) & 7;    // 0..7
    const int eu = lane;              // 0..63

    // ---- A fragments: 12 x bf16x8 = 48 regs (loop-invariant) ----
    const int arow = 16 * wid + n;
    bf16x8 A0h[2], A0l[2], AIh[2], AIl[2], AHh[2], AHl[2];
#pragma unroll
    for (int kt = 0; kt < 2; ++kt) {
        split8(&w_hh0[arow * HID + 32*kt + 8*qg], A0h[kt], A0l[kt]);
        split8(&w_ih1[arow * HID + 32*kt + 8*qg], AIh[kt], AIl[kt]);
        split8(&w_hh1[arow * HID + 32*kt + 8*qg], AHh[kt], AHl[kt]);
    }

    // ---- ew constants: unified formula, wihq=0 for layer 1 ----
    float biasq[4], wihq[4];
#pragma unroll
    for (int q = 0; q < 4; ++q) {
        int row = eu + 64 * q;
        if (el == 0) { biasq[q] = b_ih0[row] + b_hh0[row]; wihq[q] = w_ih0[row]; }
        else         { biasq[q] = b_ih1[row] + b_hh1[row]; wihq[q] = 0.f; }
    }

    // ---- frag addressing (loop-invariant) ----
    const int rb  = swz(lane) << 2;                 // read: my chunk, dword offset
    const int wkt = eu >> 5;                        // write: target kt
    const int wc4 = (swz(((eu >> 3) & 3) * 16 + eb) << 2) + ((eu & 7) >> 1);
    const bool wr = !(eu & 1);                      // even-unit lanes store pairs

    // ---- stage x; zero frag buffers ----
    for (int i = tid; i < BT * SEQ; i += 1024) {
        int b = i >> 9, t = i & (SEQ - 1);
        xs[b][t] = x[(size_t)(b0 + b) * SEQ + t];
    }
    for (int i = tid; i < 4096; i += 1024) hf[i] = 0u;
    float c = 0.f, h = 0.f;
    __syncthreads();

    // ===== prologue: h0(0) from x(0) only (h0(-1)=0); h1(-1)=0 already =====
    if (el == 0) {
        float xv = xs[eb][0];
        float ig = sigf(fmaf(xv, wihq[0], biasq[0]));
        float gg = tanhf_fast(fmaf(xv, wihq[2], biasq[2]));
        float og = sigf(fmaf(xv, wihq[3], biasq[3]));
        c = ig * gg;
        h = og * tanhf_fast(c);
    }
    {
        float hp = __int_as_float(__builtin_amdgcn_mov_dpp(__float_as_int(h), 0xB1, 0xF, 0xF, true));
        if (el == 0 && wr) {
            hf[HFB(0, 0, 0, wkt) + wc4] = packbf2(h, hp);
            hf[HFB(0, 0, 1, wkt) + wc4] = packbf2(h - trunc_bf(h), hp - trunc_bf(hp));
        }
    }
    __syncthreads();

    for (int t = 0; t < SEQ; ++t) {
        const int cur = t & 1, nxt = cur ^ 1;
        const int tx  = (t + 1 < SEQ) ? (t + 1) : (SEQ - 1);  // clamped dummy at t=511

        // ===== compute: acc0 = W_hh0.h0(t) ; acc1 = W_ih1.h0(t) + W_hh1.h1(t-1)
        f32x4 acc0, acc1;
        {
            FW B0h[2], B0l[2], B1h[2], B1l[2];
#pragma unroll
            for (int kt = 0; kt < 2; ++kt) {
                B0h[kt].q = *(const uint4*)&hf[HFB(cur, 0, 0, kt) + rb];
                B0l[kt].q = *(const uint4*)&hf[HFB(cur, 0, 1, kt) + rb];
                B1h[kt].q = *(const uint4*)&hf[HFB(cur, 1, 0, kt) + rb];
                B1l[kt].q = *(const uint4*)&hf[HFB(cur, 1, 1, kt) + rb];
            }
            f32x4 z = {0.f, 0.f, 0.f, 0.f};
            // 6 independent chains, depth 3; round-robin issue (level order).
            f32x4 c0A, c0B, c1A, c1B, c2A, c2B;
            // level 0
            c0A = MFMA(A0h[0], B0h[0].v, z);
            c0B = MFMA(A0l[0], B0h[0].v, z);
            c1A = MFMA(AIh[0], B0h[0].v, z);
            c1B = MFMA(AIl[0], B0h[0].v, z);
            c2A = MFMA(AHh[0], B1h[0].v, z);
            c2B = MFMA(AHl[0], B1h[0].v, z);
            // level 1
            c0A = MFMA(A0h[1], B0h[1].v, c0A);
            c0B = MFMA(A0l[1], B0h[1].v, c0B);
            c1A = MFMA(AIh[1], B0h[1].v, c1A);
            c1B = MFMA(AIl[1], B0h[1].v, c1B);
            c2A = MFMA(AHh[1], B1h[1].v, c2A);
            c2B = MFMA(AHl[1], B1h[1].v, c2B);
            // level 2 (hi-A x lo-B corrections, kt split across the chain pair)
            c0A = MFMA(A0h[0], B0l[0].v, c0A);
            c0B = MFMA(A0h[1], B0l[1].v, c0B);
            c1A = MFMA(AIh[0], B0l[0].v, c1A);
            c1B = MFMA(AIh[1], B0l[1].v, c1B);
            c2A = MFMA(AHh[0], B1l[0].v, c2A);
            c2B = MFMA(AHh[1], B1l[1].v, c2B);
            // merge
            acc0 = c0A + c0B;
            acc1 = (c1A + c1B) + (c2A + c2B);
        }
        // store gate pre-activations (C/D: col=n, tile-row=4qg+r); <=2-way banks
        if (n < BT) {
#pragma unroll
            for (int r = 0; r < 4; ++r) {
                gl[0][16*wid + 4*qg + r][n] = acc0[r];
                gl[1][16*wid + 4*qg + r][n] = acc1[r];
            }
        }
        __syncthreads();

        // ===== ew: this thread retires (el, eb, eu) =====
        {
            float xv = xs[eb][tx];
            float g0 = gl[el][eu      ][eb];
            float g1 = gl[el][eu +  64][eb];
            float g2 = gl[el][eu + 128][eb];
            float g3 = gl[el][eu + 192][eb];
            float ig = sigf(g0 + fmaf(xv, wihq[0], biasq[0]));
            float fg = sigf(g1 + fmaf(xv, wihq[1], biasq[1]));
            float gg = tanhf_fast(g2 + fmaf(xv, wihq[2], biasq[2]));
            float og = sigf(g3 + fmaf(xv, wihq[3], biasq[3]));
            c = fg * c + ig * gg;
            h = og * tanhf_fast(c);
            // pack (h, partner-h) into bf16 hi/lo words; even-unit lanes store
            float hp = __int_as_float(__builtin_amdgcn_mov_dpp(__float_as_int(h), 0xB1, 0xF, 0xF, true));
            if (wr) {
                hf[HFB(nxt, el, 0, wkt) + wc4] = packbf2(h, hp);
                hf[HFB(nxt, el, 1, wkt) + wc4] = packbf2(h - trunc_bf(h), hp - trunc_bf(hp));
            }
        }
        __syncthreads();
    }

    // layer-1 ew threads still hold h1(511) in register
    if (el == 1) h1last[eb][eu] = h;
    __syncthreads();

    // ===== final projection: out[b][o] = fc_b[o] + h1(511) . fc_w[o] =====
    if (tid < BT * NOUT) {
        int b = tid / NOUT, o = tid % NOUT;
        float acc = fc_b[o];
#pragma unroll
        for (int j = 0; j < HID; ++j)
            acc = fmaf(fc_w[o * HID + j], h1last[b][j], acc);
        out[(size_t)(b0 + b) * NOUT + o] = acc;
    }
}

extern "C" void kernel_launch(void* const* d_in, const int* in_sizes, int n_in,
                              void* d_out, int out_size, void* d_ws, size_t ws_size,
                              hipStream_t stream) {
    const float* x     = (const float*)d_in[0];
    const float* w_ih0 = (const float*)d_in[1];
    const float* w_hh0 = (const float*)d_in[2];
    const float* b_ih0 = (const float*)d_in[3];
    const float* b_hh0 = (const float*)d_in[4];
    const float* w_ih1 = (const float*)d_in[5];
    const float* w_hh1 = (const float*)d_in[6];
    const float* b_ih1 = (const float*)d_in[7];
    const float* b_hh1 = (const float*)d_in[8];
    const float* fc_w  = (const float*)d_in[9];
    const float* fc_b  = (const float*)d_in[10];

    const int B = in_sizes[0] / SEQ;          // 2048
    dim3 grid(B / BT);                        // 256 blocks -> 1 block/CU, 16 waves
    lstm2_fused<<<grid, 1024, 0, stream>>>(x, w_ih0, w_hh0, b_ih0, b_hh0,
                                           w_ih1, w_hh1, b_ih1, b_hh1,
                                           fc_w, fc_b, (float*)d_out);
}

// Round 12
// 749.490 us; speedup vs baseline: 1.2033x; 1.2033x over previous
//
#include <hip/hip_runtime.h>

#define BT    8      // batch tile per block
#define HID   64
#define SEQ   512
#define NOUT  12
#define GRS   9      // gate-row stride in floats (8 batches + 1 pad)

typedef float  f32x4 __attribute__((ext_vector_type(4)));
typedef _Float16 f16x8 __attribute__((ext_vector_type(8)));
typedef unsigned int u32;

union FW { f16x8 v; u32 w[4]; uint4 q; };

__device__ __forceinline__ float sigf(float x)       { return 1.f / (1.f + __expf(-x)); }
__device__ __forceinline__ float tanhf_fast(float x) { return 1.f - 2.f / (1.f + __expf(2.f * x)); }
__device__ __forceinline__ u32 packf16_2(float a, float b) {
    union { _Float16 h[2]; u32 u; } p;
    p.h[0] = (_Float16)a; p.h[1] = (_Float16)b;
    return p.u;
}
// Split 8 consecutive f32 weights into f16-hi and 4096x-scaled f16-lo fragments:
// w = Wh + 2^-12 * Wl exactly to ~2^-24 (scale keeps Wl out of f16-subnormal range).
__device__ __forceinline__ void split8_f16(const float* src, f16x8& hi, f16x8& lo) {
    float f[8];
    *(float4*)&f[0] = *(const float4*)src;
    *(float4*)&f[4] = *(const float4*)(src + 4);
    union { f16x8 v; _Float16 h[8]; } H, L;
#pragma unroll
    for (int i = 0; i < 8; ++i) {
        _Float16 a = (_Float16)f[i];
        H.h[i] = a;
        L.h[i] = (_Float16)((f[i] - (float)a) * 4096.f);
    }
    hi = H.v; lo = L.v;
}

#define MFMA(A, B, C) __builtin_amdgcn_mfma_f32_16x16x32_f16((A), (B), (C), 0, 0, 0)

// Fragment store: per (dbuf, layer, kt) a 256-dword block of 64 x 16B chunks
// (8 f16 h-values each); chunk for MFMA-lane L at swz(L) = L ^ (L>>3).
// Reads lane-linear (<=2-way banks); ew-side u32 writes also <=2-way.
#define HFB(db, ly, kt) (((((db)*2 + (ly))*2 + (kt)) << 8))
__device__ __forceinline__ int swz(int c) { return c ^ (c >> 3); }

// Round-10 champion structure (16 balanced waves, 1 block/CU, swizzled frag
// layout, gl gate round-trip, distributed ew). Single change: h is stored as
// ONE f16 per value (was bf16 hi+lo pair) and W as f16-hi + scaled-f16-lo ->
// fragment reads 8->4 per wave per step (64 KB/step LDS), MFMA 18->12.
__global__ void __launch_bounds__(1024)
lstm2_fused(
    const float* __restrict__ x,      // [B, SEQ, 1]
    const float* __restrict__ w_ih0,  // [256, 1]
    const float* __restrict__ w_hh0,  // [256, 64]
    const float* __restrict__ b_ih0,  // [256]
    const float* __restrict__ b_hh0,  // [256]
    const float* __restrict__ w_ih1,  // [256, 64]
    const float* __restrict__ w_hh1,  // [256, 64]
    const float* __restrict__ b_ih1,  // [256]
    const float* __restrict__ b_hh1,  // [256]
    const float* __restrict__ fc_w,   // [12, 64]
    const float* __restrict__ fc_b,   // [12]
    float* __restrict__ out)          // [B, 12]
{
    __shared__ float xs[BT][SEQ];          // 16 KB
    __shared__ u32   hf[2048];             // 8 KB [dbuf][layer][kt][chunk]
    __shared__ float gl[2][256][GRS];      // 18.4 KB [layer][gate-row][batch]
    __shared__ float h1last[BT][HID + 4];  // 2.1 KB

    const int tid  = threadIdx.x;
    const int wid  = tid >> 6;        // row-tile band (0..15)
    const int lane = tid & 63;
    const int n    = lane & 15;       // MFMA A-row / B-col (batch) lane index
    const int qg   = lane >> 4;       // lane k-group (0..3)
    const int b0   = blockIdx.x * BT;

    // ew role: thread <-> (layer, batch, unit)
    const int el = tid >> 9;          // 0..1
    const int eb = (tid >> 6) & 7;    // 0..7
    const int eu = lane;              // 0..63

    // ---- A fragments: 12 x f16x8 = 48 regs (loop-invariant) ----
    const int arow = 16 * wid + n;
    f16x8 A0h[2], A0l[2], AIh[2], AIl[2], AHh[2], AHl[2];
#pragma unroll
    for (int kt = 0; kt < 2; ++kt) {
        split8_f16(&w_hh0[arow * HID + 32*kt + 8*qg], A0h[kt], A0l[kt]);
        split8_f16(&w_ih1[arow * HID + 32*kt + 8*qg], AIh[kt], AIl[kt]);
        split8_f16(&w_hh1[arow * HID + 32*kt + 8*qg], AHh[kt], AHl[kt]);
    }

    // ---- ew constants: unified formula, wihq=0 for layer 1 ----
    float biasq[4], wihq[4];
#pragma unroll
    for (int q = 0; q < 4; ++q) {
        int row = eu + 64 * q;
        if (el == 0) { biasq[q] = b_ih0[row] + b_hh0[row]; wihq[q] = w_ih0[row]; }
        else         { biasq[q] = b_ih1[row] + b_hh1[row]; wihq[q] = 0.f; }
    }

    // ---- frag addressing (loop-invariant) ----
    const int rb  = swz(lane) << 2;                 // read: my chunk, dword offset
    const int wkt = eu >> 5;                        // write: target kt
    const int wc4 = (swz(((eu >> 3) & 3) * 16 + eb) << 2) + ((eu & 7) >> 1);
    const bool wr = !(eu & 1);                      // even-unit lanes store pairs

    // ---- stage x; zero frag buffers ----
    for (int i = tid; i < BT * SEQ; i += 1024) {
        int b = i >> 9, t = i & (SEQ - 1);
        xs[b][t] = x[(size_t)(b0 + b) * SEQ + t];
    }
    for (int i = tid; i < 2048; i += 1024) hf[i] = 0u;
    float c = 0.f, h = 0.f;
    __syncthreads();

    // ===== prologue: h0(0) from x(0) only (h0(-1)=0); h1(-1)=0 already =====
    if (el == 0) {
        float xv = xs[eb][0];
        float ig = sigf(fmaf(xv, wihq[0], biasq[0]));
        float gg = tanhf_fast(fmaf(xv, wihq[2], biasq[2]));
        float og = sigf(fmaf(xv, wihq[3], biasq[3]));
        c = ig * gg;
        h = og * tanhf_fast(c);
    }
    {
        float hp = __int_as_float(__builtin_amdgcn_mov_dpp(__float_as_int(h), 0xB1, 0xF, 0xF, true));
        if (el == 0 && wr) hf[HFB(0, 0, wkt) + wc4] = packf16_2(h, hp);
    }
    __syncthreads();

    const float S = 1.f / 4096.f;     // Wl descale

    for (int t = 0; t < SEQ; ++t) {
        const int cur = t & 1, nxt = cur ^ 1;
        const int tx  = (t + 1 < SEQ) ? (t + 1) : (SEQ - 1);  // clamped dummy at t=511

        // ===== compute: acc0 = W_hh0.h0(t) ; acc1 = W_ih1.h0(t) + W_hh1.h1(t-1)
        f32x4 acc0, acc1;
        {
            FW B0[2], B1[2];
#pragma unroll
            for (int kt = 0; kt < 2; ++kt) {
                B0[kt].q = *(const uint4*)&hf[HFB(cur, 0, kt) + rb];
                B1[kt].q = *(const uint4*)&hf[HFB(cur, 1, kt) + rb];
            }
            f32x4 z = {0.f, 0.f, 0.f, 0.f};
            f32x4 a0H = z, a0L = z, a1H = z, a1L = z;
#pragma unroll
            for (int kt = 0; kt < 2; ++kt) {
                a0H = MFMA(A0h[kt], B0[kt].v, a0H);
                a0L = MFMA(A0l[kt], B0[kt].v, a0L);
                a1H = MFMA(AIh[kt], B0[kt].v, a1H);
                a1L = MFMA(AIl[kt], B0[kt].v, a1L);
                a1H = MFMA(AHh[kt], B1[kt].v, a1H);
                a1L = MFMA(AHl[kt], B1[kt].v, a1L);
            }
#pragma unroll
            for (int i = 0; i < 4; ++i) {
                acc0[i] = fmaf(a0L[i], S, a0H[i]);
                acc1[i] = fmaf(a1L[i], S, a1H[i]);
            }
        }
        // store gate pre-activations (C/D: col=n, tile-row=4qg+r); <=2-way banks
        if (n < BT) {
#pragma unroll
            for (int r = 0; r < 4; ++r) {
                gl[0][16*wid + 4*qg + r][n] = acc0[r];
                gl[1][16*wid + 4*qg + r][n] = acc1[r];
            }
        }
        __syncthreads();

        // ===== ew: this thread retires (el, eb, eu) =====
        {
            float xv = xs[eb][tx];
            float g0 = gl[el][eu      ][eb];
            float g1 = gl[el][eu +  64][eb];
            float g2 = gl[el][eu + 128][eb];
            float g3 = gl[el][eu + 192][eb];
            float ig = sigf(g0 + fmaf(xv, wihq[0], biasq[0]));
            float fg = sigf(g1 + fmaf(xv, wihq[1], biasq[1]));
            float gg = tanhf_fast(g2 + fmaf(xv, wihq[2], biasq[2]));
            float og = sigf(g3 + fmaf(xv, wihq[3], biasq[3]));
            c = fg * c + ig * gg;
            h = og * tanhf_fast(c);
            // pack (h, partner-h) as two f16s; even-unit lanes store the pair
            float hp = __int_as_float(__builtin_amdgcn_mov_dpp(__float_as_int(h), 0xB1, 0xF, 0xF, true));
            if (wr) hf[HFB(nxt, el, wkt) + wc4] = packf16_2(h, hp);
        }
        __syncthreads();
    }

    // layer-1 ew threads still hold h1(511) in register
    if (el == 1) h1last[eb][eu] = h;
    __syncthreads();

    // ===== final projection: out[b][o] = fc_b[o] + h1(511) . fc_w[o] =====
    if (tid < BT * NOUT) {
        int b = tid / NOUT, o = tid % NOUT;
        float acc = fc_b[o];
#pragma unroll
        for (int j = 0; j < HID; ++j)
            acc = fmaf(fc_w[o * HID + j], h1last[b][j], acc);
        out[(size_t)(b0 + b) * NOUT + o] = acc;
    }
}

extern "C" void kernel_launch(void* const* d_in, const int* in_sizes, int n_in,
                              void* d_out, int out_size, void* d_ws, size_t ws_size,
                              hipStream_t stream) {
    const float* x     = (const float*)d_in[0];
    const float* w_ih0 = (const float*)d_in[1];
    const float* w_hh0 = (const float*)d_in[2];
    const float* b_ih0 = (const float*)d_in[3];
    const float* b_hh0 = (const float*)d_in[4];
    const float* w_ih1 = (const float*)d_in[5];
    const float* w_hh1 = (const float*)d_in[6];
    const float* b_ih1 = (const float*)d_in[7];
    const float* b_hh1 = (const float*)d_in[8];
    const float* fc_w  = (const float*)d_in[9];
    const float* fc_b  = (const float*)d_in[10];

    const int B = in_sizes[0] / SEQ;          // 2048
    dim3 grid(B / BT);                        // 256 blocks -> 1 block/CU, 16 waves
    lstm2_fused<<<grid, 1024, 0, stream>>>(x, w_ih0, w_hh0, b_ih0, b_hh0,
                                           w_ih1, w_hh1, b_ih1, b_hh1,
                                           fc_w, fc_b, (float*)d_out);
}

// Round 13
// 590.820 us; speedup vs baseline: 1.5265x; 1.2686x over previous
//
#include <hip/hip_runtime.h>

#define BT    8      // batch tile per block
#define HID   64
#define SEQ   512
#define NOUT  12
#define XST   513    // padded x row stride (per-lane batch reads conflict-free)

typedef float  f32x4 __attribute__((ext_vector_type(4)));
typedef _Float16 f16x8 __attribute__((ext_vector_type(8)));
typedef unsigned int   u32;
typedef unsigned short u16;

union FW { f16x8 v; u32 w[4]; uint4 q; };

__device__ __forceinline__ float sigf(float x)       { return 1.f / (1.f + __expf(-x)); }
__device__ __forceinline__ float tanhf_fast(float x) { return 1.f - 2.f / (1.f + __expf(2.f * x)); }
__device__ __forceinline__ u16 f16b(float a) {
    union { _Float16 f; u16 u; } p; p.f = (_Float16)a; return p.u;
}
// Split 8 consecutive f32 weights into f16-hi and 4096x-scaled f16-lo fragments:
// w = Wh + 2^-12 * Wl (scale keeps Wl out of f16-subnormal range).
__device__ __forceinline__ void split8_f16(const float* src, f16x8& hi, f16x8& lo) {
    float f[8];
    *(float4*)&f[0] = *(const float4*)src;
    *(float4*)&f[4] = *(const float4*)(src + 4);
    union { f16x8 v; _Float16 h[8]; } H, L;
#pragma unroll
    for (int i = 0; i < 8; ++i) {
        _Float16 a = (_Float16)f[i];
        H.h[i] = a;
        L.h[i] = (_Float16)((f[i] - (float)a) * 4096.f);
    }
    hi = H.v; lo = L.v;
}

#define MFMA(A, B, C) __builtin_amdgcn_mfma_f32_16x16x32_f16((A), (B), (C), 0, 0, 0)

// h-fragment store (f16): per (dbuf, layer, kt) a 256-dword block of 64 x 16B
// chunks; chunk consumed by MFMA-lane L sits at position swz(L) = L ^ (L>>3).
__device__ __forceinline__ int swz(int c) { return c ^ (c >> 3); }

// Gate-interleaved rows + layer-split ew. Tile row i <-> unit 4*wid+(i>>2),
// gate i&3, so lane (qg,n) ends the MFMA holding all 4 gates of unit 4*wid+qg
// for batch n. Lanes n<8 retire layer 0; DPP row_shr:8 hands acc1 to lanes
// n>=8 which retire layer 1. Every lane = exactly one (layer,batch,unit) ew,
// c-state in register. NO gate LDS array, ONE barrier/step.
__global__ void __launch_bounds__(1024)
lstm2_fused(
    const float* __restrict__ x,      // [B, SEQ, 1]
    const float* __restrict__ w_ih0,  // [256, 1]
    const float* __restrict__ w_hh0,  // [256, 64]
    const float* __restrict__ b_ih0,  // [256]
    const float* __restrict__ b_hh0,  // [256]
    const float* __restrict__ w_ih1,  // [256, 64]
    const float* __restrict__ w_hh1,  // [256, 64]
    const float* __restrict__ b_ih1,  // [256]
    const float* __restrict__ b_hh1,  // [256]
    const float* __restrict__ fc_w,   // [12, 64]
    const float* __restrict__ fc_b,   // [12]
    float* __restrict__ out)          // [B, 12]
{
    __shared__ float xs[BT][XST];          // 16.4 KB
    __shared__ u32   hf[2048];             // 8 KB [dbuf][layer][kt][chunk]
    __shared__ float h1last[BT][HID + 4];  // 2.1 KB

    const int tid  = threadIdx.x;
    const int wid  = tid >> 6;        // wave = unit band (units 4*wid..4*wid+3)
    const int lane = tid & 63;
    const int n    = lane & 15;       // B-col (batch) / tile-row lane index
    const int qg   = lane >> 4;       // k-group & owned-unit selector (0..3)
    const int b0   = blockIdx.x * BT;

    // ---- A fragments, gate-interleaved rows: 12 x f16x8 = 48 regs ----
    const int arow = (n & 3) * 64 + 4 * wid + (n >> 2);   // original gate row
    f16x8 A0h[2], A0l[2], AIh[2], AIl[2], AHh[2], AHl[2];
#pragma unroll
    for (int kt = 0; kt < 2; ++kt) {
        split8_f16(&w_hh0[arow * HID + 32*kt + 8*qg], A0h[kt], A0l[kt]);
        split8_f16(&w_ih1[arow * HID + 32*kt + 8*qg], AIh[kt], AIl[kt]);
        split8_f16(&w_hh1[arow * HID + 32*kt + 8*qg], AHh[kt], AHl[kt]);
    }

    // ---- ew identity: (layer ly, batch bb, unit uo) ----
    const int ly = (n >> 3) & 1;
    const int bb = n & 7;
    const int uo = 4 * wid + qg;

    float wihL[4], biaL[4];
#pragma unroll
    for (int r = 0; r < 4; ++r) {
        const int row = 64 * r + uo;
        if (ly == 0) { wihL[r] = w_ih0[row]; biaL[r] = b_ih0[row] + b_hh0[row]; }
        else         { wihL[r] = 0.f;        biaL[r] = b_ih1[row] + b_hh1[row]; }
    }

    // ---- addressing (loop-invariant) ----
    const int rb   = swz(lane) << 2;                    // frag read: dword base
    const int ktw  = uo >> 5;                           // h write: kt block
    const int qgc  = (uo & 31) >> 3;                    // consumer k-group
    const int wb16 = (ly << 10) + (ktw << 9) + (swz(qgc * 16 + bb) << 3) + (uo & 7);

    // ---- stage x; zero frag buffers ----
    for (int i = tid; i < BT * SEQ; i += 1024) {
        int b = i >> 9, t = i & (SEQ - 1);
        xs[b][t] = x[(size_t)(b0 + b) * SEQ + t];
    }
    for (int i = tid; i < 2048; i += 1024) hf[i] = 0u;
    float c = 0.f, h = 0.f;
    __syncthreads();

    // ===== prologue: h0(0) from x(0) only; h1(-1)=0 stays zeroed =====
    if (ly == 0) {
        float xv = xs[bb][0];
        float ig = sigf(fmaf(xv, wihL[0], biaL[0]));
        float gg = tanhf_fast(fmaf(xv, wihL[2], biaL[2]));
        float og = sigf(fmaf(xv, wihL[3], biaL[3]));
        c = ig * gg;
        h = og * tanhf_fast(c);
        ((u16*)hf)[wb16] = f16b(h);      // dbuf 0
    }
    __syncthreads();

    const float S = 1.f / 4096.f;        // Wl descale

    for (int t = 0; t < SEQ; ++t) {
        const int cur = t & 1, nxt = cur ^ 1;
        const int tx  = (t + 1 < SEQ) ? (t + 1) : (SEQ - 1);  // clamped dummy at t=511

        // ===== MFMA: acc0 = W_hh0.h0(t) ; acc1 = W_ih1.h0(t) + W_hh1.h1(t-1)
        f32x4 acc0, acc1;
        {
            FW B0[2], B1[2];
#pragma unroll
            for (int kt = 0; kt < 2; ++kt) {
                B0[kt].q = *(const uint4*)&hf[cur * 1024 +       kt * 256 + rb];
                B1[kt].q = *(const uint4*)&hf[cur * 1024 + 512 + kt * 256 + rb];
            }
            f32x4 z = {0.f, 0.f, 0.f, 0.f};
            f32x4 a0H = z, a0L = z, a1H = z, a1L = z;
#pragma unroll
            for (int kt = 0; kt < 2; ++kt) {
                a0H = MFMA(A0h[kt], B0[kt].v, a0H);
                a0L = MFMA(A0l[kt], B0[kt].v, a0L);
                a1H = MFMA(AIh[kt], B0[kt].v, a1H);
                a1L = MFMA(AIl[kt], B0[kt].v, a1L);
                a1H = MFMA(AHh[kt], B1[kt].v, a1H);
                a1L = MFMA(AHl[kt], B1[kt].v, a1L);
            }
#pragma unroll
            for (int i = 0; i < 4; ++i) {
                acc0[i] = fmaf(a0L[i], S, a0H[i]);
                acc1[i] = fmaf(a1L[i], S, a1H[i]);
            }
        }

        // ===== hand layer-1 gates to lanes n>=8 (row_shr:8), pick my layer =====
        f32x4 accS;
#pragma unroll
        for (int i = 0; i < 4; ++i) {
            float s = __int_as_float(__builtin_amdgcn_mov_dpp(
                          __float_as_int(acc1[i]), 0x118, 0xF, 0xF, true)); // row_shr:8
            accS[i] = ly ? s : acc0[i];
        }

        // ===== unified ew: this lane retires (ly, bb, uo) =====
        {
            float xv = xs[bb][tx];                       // wihL=0 for layer 1
            float ig = sigf(accS[0] + fmaf(xv, wihL[0], biaL[0]));
            float fg = sigf(accS[1] + fmaf(xv, wihL[1], biaL[1]));
            float gg = tanhf_fast(accS[2] + fmaf(xv, wihL[2], biaL[2]));
            float og = sigf(accS[3] + fmaf(xv, wihL[3], biaL[3]));
            c = fg * c + ig * gg;
            h = og * tanhf_fast(c);
            ((u16*)hf)[nxt * 2048 + wb16] = f16b(h);
        }
        __syncthreads();    // single barrier per step (dbuf removes WAR hazard)
    }

    // layer-1 lanes hold h1(511)
    if (ly) h1last[bb][uo] = h;
    __syncthreads();

    // ===== final projection: out[b][o] = fc_b[o] + h1(511) . fc_w[o] =====
    if (tid < BT * NOUT) {
        int b = tid / NOUT, o = tid % NOUT;
        float acc = fc_b[o];
#pragma unroll
        for (int j = 0; j < HID; ++j)
            acc = fmaf(fc_w[o * HID + j], h1last[b][j], acc);
        out[(size_t)(b0 + b) * NOUT + o] = acc;
    }
}

extern "C" void kernel_launch(void* const* d_in, const int* in_sizes, int n_in,
                              void* d_out, int out_size, void* d_ws, size_t ws_size,
                              hipStream_t stream) {
    const float* x     = (const float*)d_in[0];
    const float* w_ih0 = (const float*)d_in[1];
    const float* w_hh0 = (const float*)d_in[2];
    const float* b_ih0 = (const float*)d_in[3];
    const float* b_hh0 = (const float*)d_in[4];
    const float* w_ih1 = (const float*)d_in[5];
    const float* w_hh1 = (const float*)d_in[6];
    const float* b_ih1 = (const float*)d_in[7];
    const float* b_hh1 = (const float*)d_in[8];
    const float* fc_w  = (const float*)d_in[9];
    const float* fc_b  = (const float*)d_in[10];

    const int B = in_sizes[0] / SEQ;          // 2048
    dim3 grid(B / BT);                        // 256 blocks -> 1 block/CU, 16 waves
    lstm2_fused<<<grid, 1024, 0, stream>>>(x, w_ih0, w_hh0, b_ih0, b_hh0,
                                           w_ih1, w_hh1, b_ih1, b_hh1,
                                           fc_w, fc_b, (float*)d_out);
}

// Round 14
// 438.355 us; speedup vs baseline: 2.0574x; 1.3478x over previous
//
#include <hip/hip_runtime.h>

#define BT    8      // batch tile per block
#define HID   64
#define SEQ   512
#define NOUT  12
#define XST   513    // padded x row stride (per-lane batch reads conflict-free)

typedef float  f32x4 __attribute__((ext_vector_type(4)));
typedef _Float16 f16x8 __attribute__((ext_vector_type(8)));
typedef unsigned int   u32;
typedef unsigned short u16;

union FW { f16x8 v; u32 w[4]; uint4 q; };

// v_rcp_f32 (1 ulp) instead of IEEE divide (~10 inst + long chain).
__device__ __forceinline__ float rcpf(float x) { return __builtin_amdgcn_rcpf(x); }
__device__ __forceinline__ float sigf(float x)       { return rcpf(1.f + __expf(-x)); }
__device__ __forceinline__ float tanhf_fast(float x) { return fmaf(-2.f, rcpf(1.f + __expf(2.f * x)), 1.f); }
__device__ __forceinline__ u16 f16b(float a) {
    union { _Float16 f; u16 u; } p; p.f = (_Float16)a; return p.u;
}
// Split 8 consecutive f32 weights into f16-hi and 4096x-scaled f16-lo fragments:
// w = Wh + 2^-12 * Wl (scale keeps Wl out of f16-subnormal range).
__device__ __forceinline__ void split8_f16(const float* src, f16x8& hi, f16x8& lo) {
    float f[8];
    *(float4*)&f[0] = *(const float4*)src;
    *(float4*)&f[4] = *(const float4*)(src + 4);
    union { f16x8 v; _Float16 h[8]; } H, L;
#pragma unroll
    for (int i = 0; i < 8; ++i) {
        _Float16 a = (_Float16)f[i];
        H.h[i] = a;
        L.h[i] = (_Float16)((f[i] - (float)a) * 4096.f);
    }
    hi = H.v; lo = L.v;
}

#define MFMA(A, B, C) __builtin_amdgcn_mfma_f32_16x16x32_f16((A), (B), (C), 0, 0, 0)

// h-fragment store (f16): per (dbuf, layer, kt) a 256-dword block of 64 x 16B
// chunks; chunk consumed by MFMA-lane L sits at position swz(L) = L ^ (L>>3).
__device__ __forceinline__ int swz(int c) { return c ^ (c >> 3); }

// r13 champion structure (gate-interleaved rows, layer-split ew via row_shr:8,
// no gate LDS array, one barrier/step). Round-14 edits: (1) all sigmoid/tanh
// divisions -> v_rcp_f32; (2) biases preloaded into the MFMA C-in registers
// (lane-constant by C/D mapping), removing the bias adds from the ew chain.
__global__ void __launch_bounds__(1024)
lstm2_fused(
    const float* __restrict__ x,      // [B, SEQ, 1]
    const float* __restrict__ w_ih0,  // [256, 1]
    const float* __restrict__ w_hh0,  // [256, 64]
    const float* __restrict__ b_ih0,  // [256]
    const float* __restrict__ b_hh0,  // [256]
    const float* __restrict__ w_ih1,  // [256, 64]
    const float* __restrict__ w_hh1,  // [256, 64]
    const float* __restrict__ b_ih1,  // [256]
    const float* __restrict__ b_hh1,  // [256]
    const float* __restrict__ fc_w,   // [12, 64]
    const float* __restrict__ fc_b,   // [12]
    float* __restrict__ out)          // [B, 12]
{
    __shared__ float xs[BT][XST];          // 16.4 KB
    __shared__ u32   hf[2048];             // 8 KB [dbuf][layer][kt][chunk]
    __shared__ float h1last[BT][HID + 4];  // 2.1 KB

    const int tid  = threadIdx.x;
    const int wid  = tid >> 6;        // wave = unit band (units 4*wid..4*wid+3)
    const int lane = tid & 63;
    const int n    = lane & 15;       // B-col (batch) / tile-row lane index
    const int qg   = lane >> 4;       // k-group & owned-unit selector (0..3)
    const int b0   = blockIdx.x * BT;

    // ---- A fragments, gate-interleaved rows: 12 x f16x8 = 48 regs ----
    const int arow = (n & 3) * 64 + 4 * wid + (n >> 2);   // original gate row
    f16x8 A0h[2], A0l[2], AIh[2], AIl[2], AHh[2], AHl[2];
#pragma unroll
    for (int kt = 0; kt < 2; ++kt) {
        split8_f16(&w_hh0[arow * HID + 32*kt + 8*qg], A0h[kt], A0l[kt]);
        split8_f16(&w_ih1[arow * HID + 32*kt + 8*qg], AIh[kt], AIl[kt]);
        split8_f16(&w_hh1[arow * HID + 32*kt + 8*qg], AHh[kt], AHl[kt]);
    }

    // ---- ew identity: (layer ly, batch bb, unit uo) ----
    const int ly = (n >> 3) & 1;
    const int bb = n & 7;
    const int uo = 4 * wid + qg;

    // MFMA C-in biases (indexed by OUTPUT identity: unit uo, gate r; lane-const)
    float bias0v[4], bias1v[4], wihL[4];
#pragma unroll
    for (int r = 0; r < 4; ++r) {
        const int row = 64 * r + uo;
        bias0v[r] = b_ih0[row] + b_hh0[row];
        bias1v[r] = b_ih1[row] + b_hh1[row];
        wihL[r]   = (ly == 0) ? w_ih0[row] : 0.f;
    }

    // ---- addressing (loop-invariant) ----
    const int rb   = swz(lane) << 2;                    // frag read: dword base
    const int ktw  = uo >> 5;                           // h write: kt block
    const int qgc  = (uo & 31) >> 3;                    // consumer k-group
    const int wb16 = (ly << 10) + (ktw << 9) + (swz(qgc * 16 + bb) << 3) + (uo & 7);

    // ---- stage x; zero frag buffers ----
    for (int i = tid; i < BT * SEQ; i += 1024) {
        int b = i >> 9, t = i & (SEQ - 1);
        xs[b][t] = x[(size_t)(b0 + b) * SEQ + t];
    }
    for (int i = tid; i < 2048; i += 1024) hf[i] = 0u;
    float c = 0.f, h = 0.f;
    __syncthreads();

    // ===== prologue: h0(0) from x(0) only; h1(-1)=0 stays zeroed =====
    if (ly == 0) {
        float xv = xs[bb][0];
        float ig = sigf(fmaf(xv, wihL[0], bias0v[0]));
        float gg = tanhf_fast(fmaf(xv, wihL[2], bias0v[2]));
        float og = sigf(fmaf(xv, wihL[3], bias0v[3]));
        c = ig * gg;
        h = og * tanhf_fast(c);
        ((u16*)hf)[wb16] = f16b(h);      // dbuf 0
    }
    __syncthreads();

    const float S = 1.f / 4096.f;        // Wl descale

    for (int t = 0; t < SEQ; ++t) {
        const int cur = t & 1, nxt = cur ^ 1;
        const int tx  = (t + 1 < SEQ) ? (t + 1) : (SEQ - 1);  // clamped dummy at t=511

        // ===== MFMA: acc0 = bias0 + W_hh0.h0(t)
        //            acc1 = bias1 + W_ih1.h0(t) + W_hh1.h1(t-1)
        f32x4 acc0, acc1;
        {
            FW B0[2], B1[2];
#pragma unroll
            for (int kt = 0; kt < 2; ++kt) {
                B0[kt].q = *(const uint4*)&hf[cur * 1024 +       kt * 256 + rb];
                B1[kt].q = *(const uint4*)&hf[cur * 1024 + 512 + kt * 256 + rb];
            }
            f32x4 z = {0.f, 0.f, 0.f, 0.f};
            f32x4 a0H = {bias0v[0], bias0v[1], bias0v[2], bias0v[3]};
            f32x4 a1H = {bias1v[0], bias1v[1], bias1v[2], bias1v[3]};
            f32x4 a0L = z, a1L = z;
#pragma unroll
            for (int kt = 0; kt < 2; ++kt) {
                a0H = MFMA(A0h[kt], B0[kt].v, a0H);
                a0L = MFMA(A0l[kt], B0[kt].v, a0L);
                a1H = MFMA(AIh[kt], B0[kt].v, a1H);
                a1L = MFMA(AIl[kt], B0[kt].v, a1L);
                a1H = MFMA(AHh[kt], B1[kt].v, a1H);
                a1L = MFMA(AHl[kt], B1[kt].v, a1L);
            }
#pragma unroll
            for (int i = 0; i < 4; ++i) {
                acc0[i] = fmaf(a0L[i], S, a0H[i]);
                acc1[i] = fmaf(a1L[i], S, a1H[i]);
            }
        }

        // ===== hand layer-1 gates to lanes n>=8 (row_shr:8), pick my layer =====
        f32x4 accS;
#pragma unroll
        for (int i = 0; i < 4; ++i) {
            float s = __int_as_float(__builtin_amdgcn_mov_dpp(
                          __float_as_int(acc1[i]), 0x118, 0xF, 0xF, true)); // row_shr:8
            accS[i] = ly ? s : acc0[i];
        }

        // ===== unified ew: this lane retires (ly, bb, uo) =====
        {
            float xv = xs[bb][tx];                       // wihL=0 for layer 1
            float ig = sigf(fmaf(xv, wihL[0], accS[0]));
            float fg = sigf(fmaf(xv, wihL[1], accS[1]));
            float gg = tanhf_fast(fmaf(xv, wihL[2], accS[2]));
            float og = sigf(fmaf(xv, wihL[3], accS[3]));
            c = fg * c + ig * gg;
            h = og * tanhf_fast(c);
            ((u16*)hf)[nxt * 2048 + wb16] = f16b(h);
        }
        __syncthreads();    // single barrier per step (dbuf removes WAR hazard)
    }

    // layer-1 lanes hold h1(511)
    if (ly) h1last[bb][uo] = h;
    __syncthreads();

    // ===== final projection: out[b][o] = fc_b[o] + h1(511) . fc_w[o] =====
    if (tid < BT * NOUT) {
        int b = tid / NOUT, o = tid % NOUT;
        float acc = fc_b[o];
#pragma unroll
        for (int j = 0; j < HID; ++j)
            acc = fmaf(fc_w[o * HID + j], h1last[b][j], acc);
        out[(size_t)(b0 + b) * NOUT + o] = acc;
    }
}

extern "C" void kernel_launch(void* const* d_in, const int* in_sizes, int n_in,
                              void* d_out, int out_size, void* d_ws, size_t ws_size,
                              hipStream_t stream) {
    const float* x     = (const float*)d_in[0];
    const float* w_ih0 = (const float*)d_in[1];
    const float* w_hh0 = (const float*)d_in[2];
    const float* b_ih0 = (const float*)d_in[3];
    const float* b_hh0 = (const float*)d_in[4];
    const float* w_ih1 = (const float*)d_in[5];
    const float* w_hh1 = (const float*)d_in[6];
    const float* b_ih1 = (const float*)d_in[7];
    const float* b_hh1 = (const float*)d_in[8];
    const float* fc_w  = (const float*)d_in[9];
    const float* fc_b  = (const float*)d_in[10];

    const int B = in_sizes[0] / SEQ;          // 2048
    dim3 grid(B / BT);                        // 256 blocks -> 1 block/CU, 16 waves
    lstm2_fused<<<grid, 1024, 0, stream>>>(x, w_ih0, w_hh0, b_ih0, b_hh0,
                                           w_ih1, w_hh1, b_ih1, b_hh1,
                                           fc_w, fc_b, (float*)d_out);
}

// Round 16
// 405.938 us; speedup vs baseline: 2.2217x; 1.0799x over previous
//
#include <hip/hip_runtime.h>

#define BT    8      // batch tile per block
#define HID   64
#define SEQ   512
#define NOUT  12
#define XST   514    // x row stride: 512 data + 1 dup col + pad

typedef float  f32x4 __attribute__((ext_vector_type(4)));
typedef _Float16 f16x8 __attribute__((ext_vector_type(8)));
typedef unsigned int   u32;
typedef unsigned short u16;

union FW { f16x8 v; u32 w[4]; uint4 q; };

__device__ __forceinline__ float rcpf(float x) { return __builtin_amdgcn_rcpf(x); }
__device__ __forceinline__ float e2(float x)   { return __builtin_amdgcn_exp2f(x); }
__device__ __forceinline__ u16 f16b(float a) {
    union { _Float16 f; u16 u; } p; p.f = (_Float16)a; return p.u;
}
// Split 8 consecutive f32 weights (pre-scaled by `scale`) into f16-hi and
// 4096x-scaled f16-lo fragments: w*scale = Wh + 2^-12 * Wl.
__device__ __forceinline__ void split8_f16(const float* src, float scale, f16x8& hi, f16x8& lo) {
    float f[8];
    *(float4*)&f[0] = *(const float4*)src;
    *(float4*)&f[4] = *(const float4*)(src + 4);
    union { f16x8 v; _Float16 h[8]; } H, L;
#pragma unroll
    for (int i = 0; i < 8; ++i) {
        float s = f[i] * scale;
        _Float16 a = (_Float16)s;
        H.h[i] = a;
        L.h[i] = (_Float16)((s - (float)a) * 4096.f);
    }
    hi = H.v; lo = L.v;
}

#define MFMA(A, B, C) __builtin_amdgcn_mfma_f32_16x16x32_f16((A), (B), (C), 0, 0, 0)

// h-fragment chunk for MFMA-lane L at position swz(L) = L ^ (L>>3).
__device__ __forceinline__ int swz(int c) { return c ^ (c >> 3); }

// r14 champion structure (gate-interleaved rows, layer-split ew via row_shr:8,
// bias in MFMA C-in, one barrier/step). Round-15 edits: (1) log2e folded into
// weights/biases (gate g: 2*log2e) -> bare v_exp_f32 in all gate sigmoids/tanh;
// (2) t-loop unrolled x2 -> all LDS frag addresses are base+literal-offset;
// (3) xs column 512 duplicates 511 -> no tx clamp.
__global__ void __launch_bounds__(1024)
lstm2_fused(
    const float* __restrict__ x,      // [B, SEQ, 1]
    const float* __restrict__ w_ih0,  // [256, 1]
    const float* __restrict__ w_hh0,  // [256, 64]
    const float* __restrict__ b_ih0,  // [256]
    const float* __restrict__ b_hh0,  // [256]
    const float* __restrict__ w_ih1,  // [256, 64]
    const float* __restrict__ w_hh1,  // [256, 64]
    const float* __restrict__ b_ih1,  // [256]
    const float* __restrict__ b_hh1,  // [256]
    const float* __restrict__ fc_w,   // [12, 64]
    const float* __restrict__ fc_b,   // [12]
    float* __restrict__ out)          // [B, 12]
{
    __shared__ float xs[BT][XST];          // 16.4 KB
    __shared__ u32   hf[2048];             // 8 KB [dbuf][layer][kt][chunk]
    __shared__ float h1last[BT][HID + 4];  // 2.1 KB

    const int tid  = threadIdx.x;
    const int wid  = tid >> 6;        // wave = unit band (units 4*wid..4*wid+3)
    const int lane = tid & 63;
    const int n    = lane & 15;       // B-col (batch) / tile-row lane index
    const int qg   = lane >> 4;       // k-group & owned-unit selector (0..3)
    const int b0   = blockIdx.x * BT;

    const float L2E  = 1.44269504088896340736f;
    const float TL2E = 2.f * L2E;

    // ---- A fragments, gate-interleaved rows, log2e-scaled: 12 x f16x8 ----
    const int ag   = n & 3;                               // gate of this A row
    const int arow = ag * 64 + 4 * wid + (n >> 2);        // original gate row
    const float asc = (ag == 2) ? TL2E : L2E;             // row scale
    f16x8 A0h[2], A0l[2], AIh[2], AIl[2], AHh[2], AHl[2];
#pragma unroll
    for (int kt = 0; kt < 2; ++kt) {
        split8_f16(&w_hh0[arow * HID + 32*kt + 8*qg], asc, A0h[kt], A0l[kt]);
        split8_f16(&w_ih1[arow * HID + 32*kt + 8*qg], asc, AIh[kt], AIl[kt]);
        split8_f16(&w_hh1[arow * HID + 32*kt + 8*qg], asc, AHh[kt], AHl[kt]);
    }

    // ---- ew identity: (layer ly, batch bb, unit uo) ----
    const int ly = (n >> 3) & 1;
    const int bb = n & 7;
    const int uo = 4 * wid + qg;

    // MFMA C-in biases + wih, scaled to the exp2 domain (gate r scale sc[r])
    float bias0v[4], bias1v[4], wihL[4];
#pragma unroll
    for (int r = 0; r < 4; ++r) {
        const int row = 64 * r + uo;
        const float sc = (r == 2) ? TL2E : L2E;
        bias0v[r] = (b_ih0[row] + b_hh0[row]) * sc;
        bias1v[r] = (b_ih1[row] + b_hh1[row]) * sc;
        wihL[r]   = (ly == 0) ? w_ih0[row] * sc : 0.f;
    }

    // ---- addressing (loop-invariant) ----
    const int rb   = swz(lane) << 2;                    // frag read: dword base
    const int ktw  = uo >> 5;                           // h write: kt block
    const int qgc  = (uo & 31) >> 3;                    // consumer k-group
    const int wb16 = (ly << 10) + (ktw << 9) + (swz(qgc * 16 + bb) << 3) + (uo & 7);
    const char* hfB = (const char*)hf + rb * 4;         // read base (bytes)
    u16*        hwB = (u16*)hf + wb16;                  // write base

    // ---- stage x (+dup col 512); zero frag buffers ----
    for (int i = tid; i < BT * SEQ; i += 1024) {
        int b = i >> 9, t = i & (SEQ - 1);
        xs[b][t] = x[(size_t)(b0 + b) * SEQ + t];
    }
    if (tid < BT) xs[tid][SEQ] = x[(size_t)(b0 + tid) * SEQ + (SEQ - 1)];
    for (int i = tid; i < 2048; i += 1024) hf[i] = 0u;
    float c = 0.f, h = 0.f;
    __syncthreads();

    // ===== prologue: h0(0) from x(0) only; h1(-1)=0 stays zeroed =====
    if (ly == 0) {
        float xv = xs[bb][0];
        float ig = rcpf(1.f + e2(-fmaf(xv, wihL[0], bias0v[0])));
        float gg = fmaf(-2.f, rcpf(1.f + e2(fmaf(xv, wihL[2], bias0v[2]))), 1.f);
        float og = rcpf(1.f + e2(-fmaf(xv, wihL[3], bias0v[3])));
        c = ig * gg;
        h = og * fmaf(-2.f, rcpf(1.f + e2(c * TL2E)), 1.f);
        hwB[0] = f16b(h);                // dbuf 0
    }
    __syncthreads();

    const float S = 1.f / 4096.f;        // Wl descale
    const float* xp = &xs[bb][1];        // x(t+1) for t = 0

#define STEP(CUR, NXT, XV)                                                     \
    {                                                                          \
        const float xv = (XV);                                                 \
        FW B00, B01, B10, B11;                                                 \
        B00.q = *(const uint4*)(hfB + (CUR)*4096 + 0);                         \
        B01.q = *(const uint4*)(hfB + (CUR)*4096 + 1024);                      \
        B10.q = *(const uint4*)(hfB + (CUR)*4096 + 2048);                      \
        B11.q = *(const uint4*)(hfB + (CUR)*4096 + 3072);                      \
        f32x4 z4 = {0.f, 0.f, 0.f, 0.f};                                       \
        f32x4 a0H = {bias0v[0], bias0v[1], bias0v[2], bias0v[3]};              \
        f32x4 a1H = {bias1v[0], bias1v[1], bias1v[2], bias1v[3]};              \
        f32x4 a0L = z4, a1L = z4;                                              \
        a0H = MFMA(A0h[0], B00.v, a0H);  a0L = MFMA(A0l[0], B00.v, a0L);       \
        a1H = MFMA(AIh[0], B00.v, a1H);  a1L = MFMA(AIl[0], B00.v, a1L);       \
        a1H = MFMA(AHh[0], B10.v, a1H);  a1L = MFMA(AHl[0], B10.v, a1L);       \
        a0H = MFMA(A0h[1], B01.v, a0H);  a0L = MFMA(A0l[1], B01.v, a0L);       \
        a1H = MFMA(AIh[1], B01.v, a1H);  a1L = MFMA(AIl[1], B01.v, a1L);       \
        a1H = MFMA(AHh[1], B11.v, a1H);  a1L = MFMA(AHl[1], B11.v, a1L);       \
        f32x4 acc0, acc1, accS;                                                \
        _Pragma("unroll")                                                      \
        for (int i = 0; i < 4; ++i) {                                          \
            acc0[i] = fmaf(a0L[i], S, a0H[i]);                                 \
            acc1[i] = fmaf(a1L[i], S, a1H[i]);                                 \
        }                                                                      \
        _Pragma("unroll")                                                      \
        for (int i = 0; i < 4; ++i) {                                          \
            float s = __int_as_float(__builtin_amdgcn_mov_dpp(                 \
                          __float_as_int(acc1[i]), 0x118, 0xF, 0xF, true));    \
            accS[i] = ly ? s : acc0[i];                                        \
        }                                                                      \
        float ig = rcpf(1.f + e2(-fmaf(xv, wihL[0], accS[0])));                \
        float fg = rcpf(1.f + e2(-fmaf(xv, wihL[1], accS[1])));                \
        float gg = fmaf(-2.f, rcpf(1.f + e2(fmaf(xv, wihL[2], accS[2]))), 1.f);\
        float og = rcpf(1.f + e2(-fmaf(xv, wihL[3], accS[3])));                \
        c = fg * c + ig * gg;                                                  \
        h = og * fmaf(-2.f, rcpf(1.f + e2(c * TL2E)), 1.f);                    \
        hwB[(NXT) * 2048] = f16b(h);                                           \
        __syncthreads();                                                       \
    }

    for (int t2 = 0; t2 < SEQ; t2 += 2) {
        STEP(0, 1, xp[0]);
        STEP(1, 0, xp[1]);
        xp += 2;
    }
#undef STEP

    // layer-1 lanes hold h1(511)
    if (ly) h1last[bb][uo] = h;
    __syncthreads();

    // ===== final projection: out[b][o] = fc_b[o] + h1(511) . fc_w[o] =====
    if (tid < BT * NOUT) {
        int b = tid / NOUT, o = tid % NOUT;
        float acc = fc_b[o];
#pragma unroll
        for (int j = 0; j < HID; ++j)
            acc = fmaf(fc_w[o * HID + j], h1last[b][j], acc);
        out[(size_t)(b0 + b) * NOUT + o] = acc;
    }
}

extern "C" void kernel_launch(void* const* d_in, const int* in_sizes, int n_in,
                              void* d_out, int out_size, void* d_ws, size_t ws_size,
                              hipStream_t stream) {
    const float* x     = (const float*)d_in[0];
    const float* w_ih0 = (const float*)d_in[1];
    const float* w_hh0 = (const float*)d_in[2];
    const float* b_ih0 = (const float*)d_in[3];
    const float* b_hh0 = (const float*)d_in[4];
    const float* w_ih1 = (const float*)d_in[5];
    const float* w_hh1 = (const float*)d_in[6];
    const float* b_ih1 = (const float*)d_in[7];
    const float* b_hh1 = (const float*)d_in[8];
    const float* fc_w  = (const float*)d_in[9];
    const float* fc_b  = (const float*)d_in[10];

    const int B = in_sizes[0] / SEQ;          // 2048
    dim3 grid(B / BT);                        // 256 blocks -> 1 block/CU, 16 waves
    lstm2_fused<<<grid, 1024, 0, stream>>>(x, w_ih0, w_hh0, b_ih0, b_hh0,
                                           w_ih1, w_hh1, b_ih1, b_hh1,
                                           fc_w, fc_b, (float*)d_out);
}